// Round 1
// baseline (17104.720 us; speedup 1.0000x reference)
//
#include <hip/hip_runtime.h>
#include <cstdint>
#include <cstddef>

#define D_    2048
#define T_    4096
#define B_    2
#define KSEL  1024
#define FF_   8192
#define NTOK  (B_*T_)      // 8192
#define MSEL  (B_*KSEL)    // 2048
#define HD_   128
#define H_    16

__device__ __forceinline__ float sigmoidf_(float x){ return 1.0f/(1.0f+expf(-x)); }
__device__ __forceinline__ float geluf_(float x){ return 0.5f*x*(1.0f+erff(x*0.70710678118654752440f)); }

// ---------------- router logits: logits[row] = hs[row,:] . router_w (fp64 accum) ----------------
__global__ __launch_bounds__(256) void k_router_logits(const float* __restrict__ hs,
        const float* __restrict__ rw, float* __restrict__ logits) {
  int row = blockIdx.x;
  const float4* x = (const float4*)(hs + (size_t)row * D_);
  const float4* w = (const float4*)rw;
  int tid = threadIdx.x;
  double acc = 0.0;
  for (int i = tid; i < D_/4; i += 256) {
    float4 a = x[i]; float4 b = w[i];
    acc += (double)a.x*b.x + (double)a.y*b.y + (double)a.z*b.z + (double)a.w*b.w;
  }
  __shared__ double red[256];
  red[tid] = acc; __syncthreads();
  for (int s = 128; s > 0; s >>= 1) { if (tid < s) red[tid] += red[tid+s]; __syncthreads(); }
  if (tid == 0) logits[row] = (float)red[0];
}

// ---------------- top-k via bitonic sort of packed keys (desc value, tie -> lower idx) ----------
__global__ __launch_bounds__(1024) void k_topk(const float* __restrict__ logits,
      int* __restrict__ idx_out, float* __restrict__ g_out, float* __restrict__ flags) {
  int b = blockIdx.x;
  int tid = threadIdx.x;
  __shared__ unsigned long long keys[T_];
  for (int i = tid; i < T_; i += 1024) {
    float v = logits[b*T_ + i];
    unsigned u = __float_as_uint(v);
    unsigned s = (u & 0x80000000u) ? ~u : (u | 0x80000000u);
    keys[i] = ((unsigned long long)s << 32) | (unsigned long long)(0xFFFFFFFFu - (unsigned)i);
    flags[b*T_ + i] = 0.0f;
  }
  __syncthreads();
  for (int size = 2; size <= T_; size <<= 1) {
    for (int stride = size >> 1; stride > 0; stride >>= 1) {
      for (int i = tid; i < T_; i += 1024) {
        int l = i ^ stride;
        if (l > i) {
          unsigned long long a = keys[i], c = keys[l];
          bool up = ((i & size) == 0);
          bool sw = up ? (a < c) : (a > c);   // descending overall
          if (sw) { keys[i] = c; keys[l] = a; }
        }
      }
      __syncthreads();
    }
  }
  if (tid < KSEL) {
    unsigned long long kk = keys[tid];
    unsigned s = (unsigned)(kk >> 32);
    unsigned u = (s & 0x80000000u) ? (s & 0x7FFFFFFFu) : ~s;
    float v = __uint_as_float(u);
    int t = (int)(0xFFFFFFFFu - (unsigned)(kk & 0xFFFFFFFFull));
    idx_out[b*KSEL + tid] = t;
    g_out[b*KSEL + tid] = sigmoidf_(v);
    flags[b*T_ + t] = 1.0f;
  }
}

// ---------------- router losses (bce + z), single block ----------------
__global__ __launch_bounds__(256) void k_router_loss(const float* __restrict__ logits,
      const float* __restrict__ flags, float* __restrict__ outp) {
  int tid = threadIdx.x;
  double bce = 0.0, z = 0.0;
  for (int i = tid; i < NTOK; i += 256) {
    float x = logits[i], y = flags[i];
    bce += (double)(fmaxf(x, 0.0f) - x*y + log1pf(expf(-fabsf(x))));
    z   += (double)x * (double)x;
  }
  __shared__ double r1[256], r2[256];
  r1[tid] = bce; r2[tid] = z; __syncthreads();
  for (int s = 128; s > 0; s >>= 1) {
    if (tid < s) { r1[tid] += r1[tid+s]; r2[tid] += r2[tid+s]; }
    __syncthreads();
  }
  if (tid == 0) {
    outp[0] = (float)(r1[0] / (double)NTOK);
    outp[1] = (float)(r2[0] / (double)NTOK * 1e-4);
  }
}

// ---------------- generic BCE (predictor loss) ----------------
__global__ __launch_bounds__(256) void k_bce(const float* __restrict__ x,
      const float* __restrict__ y, float* __restrict__ outp) {
  int tid = threadIdx.x;
  double bce = 0.0;
  for (int i = tid; i < NTOK; i += 256) {
    float xv = x[i], yv = y[i];
    bce += (double)(fmaxf(xv, 0.0f) - xv*yv + log1pf(expf(-fabsf(xv))));
  }
  __shared__ double r1[256];
  r1[tid] = bce; __syncthreads();
  for (int s = 128; s > 0; s >>= 1) { if (tid < s) r1[tid] += r1[tid+s]; __syncthreads(); }
  if (tid == 0) outp[0] = (float)(r1[0] / (double)NTOK);
}

// ---------------- copy hidden_states -> d_out ----------------
__global__ __launch_bounds__(256) void k_copy(const float4* __restrict__ src,
      float4* __restrict__ dst, int n4) {
  int i = blockIdx.x*256 + threadIdx.x;
  int stride = gridDim.x*256;
  for (; i < n4; i += stride) dst[i] = src[i];
}

// ---------------- gather selected rows + RMSNorm(ln1) ----------------
__global__ __launch_bounds__(256) void k_gather_rms(const float* __restrict__ hs,
      const int* __restrict__ idx, const float* __restrict__ w,
      float* __restrict__ xsel, float* __restrict__ xa) {
  int row = blockIdx.x;               // 0..MSEL-1
  int b = row >> 10;
  int t = idx[row];
  const float4* src = (const float4*)(hs + ((size_t)(b*T_ + t)) * D_);
  float4* xs4 = (float4*)(xsel + (size_t)row*D_);
  float4* xa4 = (float4*)(xa  + (size_t)row*D_);
  const float4* w4 = (const float4*)w;
  int tid = threadIdx.x;
  float4 loc[2];
  double ss = 0.0;
  #pragma unroll
  for (int j = 0; j < 2; ++j) {
    float4 v = src[tid + j*256];
    loc[j] = v;
    ss += (double)v.x*v.x + (double)v.y*v.y + (double)v.z*v.z + (double)v.w*v.w;
  }
  __shared__ double red[256];
  red[tid] = ss; __syncthreads();
  for (int s = 128; s > 0; s >>= 1) { if (tid < s) red[tid] += red[tid+s]; __syncthreads(); }
  float rms = (float)(1.0 / sqrt(red[0] / (double)D_ + 1e-6));
  #pragma unroll
  for (int j = 0; j < 2; ++j) {
    float4 v = loc[j];
    float4 ww = w4[tid + j*256];
    xs4[tid + j*256] = v;
    float4 o; o.x = v.x*rms*ww.x; o.y = v.y*rms*ww.y; o.z = v.z*rms*ww.z; o.w = v.w*rms*ww.w;
    xa4[tid + j*256] = o;
  }
}

// ---------------- plain RMSNorm ----------------
__global__ __launch_bounds__(256) void k_rms(const float* __restrict__ x,
      const float* __restrict__ w, float* __restrict__ y) {
  int row = blockIdx.x;
  const float4* xr = (const float4*)(x + (size_t)row*D_);
  float4* yr = (float4*)(y + (size_t)row*D_);
  const float4* w4 = (const float4*)w;
  int tid = threadIdx.x;
  float4 loc[2];
  double ss = 0.0;
  #pragma unroll
  for (int j = 0; j < 2; ++j) {
    float4 v = xr[tid + j*256];
    loc[j] = v;
    ss += (double)v.x*v.x + (double)v.y*v.y + (double)v.z*v.z + (double)v.w*v.w;
  }
  __shared__ double red[256];
  red[tid] = ss; __syncthreads();
  for (int s = 128; s > 0; s >>= 1) { if (tid < s) red[tid] += red[tid+s]; __syncthreads(); }
  float rms = (float)(1.0 / sqrt(red[0] / (double)D_ + 1e-6));
  #pragma unroll
  for (int j = 0; j < 2; ++j) {
    float4 v = loc[j];
    float4 ww = w4[tid + j*256];
    float4 o; o.x = v.x*rms*ww.x; o.y = v.y*rms*ww.y; o.z = v.z*rms*ww.z; o.w = v.w*rms*ww.w;
    yr[tid + j*256] = o;
  }
}

// ---------------- generic 64x64 fp32 GEMM, MODE: 0=+bias, 1=+residual, 2=gelu(+bias) ----------
template<int MODE>
__global__ __launch_bounds__(256) void k_gemm(const float* __restrict__ A, const float* __restrict__ Bm,
    const float* __restrict__ bias, const float* __restrict__ res, float* __restrict__ C,
    int M, int N, int K) {
  __shared__ float As[16][68];
  __shared__ float Bs[16][68];
  int tid = threadIdx.x;
  int bx = blockIdx.x, by = blockIdx.y;
  int row0 = by*64, col0 = bx*64;
  int am = tid >> 2, ak = (tid & 3) << 2;   // A stage: row am, k ak..ak+3
  int bk = tid >> 4, bn = (tid & 15) << 2;  // B stage: k bk, col bn..bn+3
  int tx = tid & 15, ty = tid >> 4;
  const float* Ap = A + (size_t)(row0 + am)*K + ak;
  const float* Bp = Bm + (size_t)bk*N + col0 + bn;
  float acc[4][4];
  #pragma unroll
  for (int i = 0; i < 4; ++i)
    #pragma unroll
    for (int j = 0; j < 4; ++j) acc[i][j] = 0.0f;
  for (int kt = 0; kt < K; kt += 16) {
    float4 av = *(const float4*)(Ap + kt);
    float4 bv = *(const float4*)(Bp + (size_t)kt*N);
    As[ak+0][am] = av.x; As[ak+1][am] = av.y; As[ak+2][am] = av.z; As[ak+3][am] = av.w;
    *(float4*)&Bs[bk][bn] = bv;
    __syncthreads();
    #pragma unroll
    for (int kk = 0; kk < 16; ++kk) {
      float4 a4 = *(const float4*)&As[kk][ty<<2];
      float4 b4 = *(const float4*)&Bs[kk][tx<<2];
      float a[4] = {a4.x, a4.y, a4.z, a4.w};
      float bb[4] = {b4.x, b4.y, b4.z, b4.w};
      #pragma unroll
      for (int i = 0; i < 4; ++i)
        #pragma unroll
        for (int j = 0; j < 4; ++j) acc[i][j] = fmaf(a[i], bb[j], acc[i][j]);
    }
    __syncthreads();
  }
  #pragma unroll
  for (int i = 0; i < 4; ++i) {
    int r = row0 + (ty<<2) + i;
    #pragma unroll
    for (int j = 0; j < 4; ++j) {
      int c = col0 + (tx<<2) + j;
      float v = acc[i][j];
      if (MODE == 0) v += bias[c];
      if (MODE == 1) v += res[(size_t)r*N + c];
      if (MODE == 2) { v += bias[c]; v = geluf_(v); }
      C[(size_t)r*N + c] = v;
    }
  }
}

// ---------------- dual GEMM for gate/up, epilogue silu(g)*u ----------------
__global__ __launch_bounds__(256) void k_dualgemm(const float* __restrict__ A,
    const float* __restrict__ Bg, const float* __restrict__ Bu,
    float* __restrict__ C, int M, int N, int K) {
  __shared__ float As[16][68];
  __shared__ float Bgs[16][68];
  __shared__ float Bus[16][68];
  int tid = threadIdx.x;
  int bx = blockIdx.x, by = blockIdx.y;
  int row0 = by*64, col0 = bx*64;
  int am = tid >> 2, ak = (tid & 3) << 2;
  int bk = tid >> 4, bn = (tid & 15) << 2;
  int tx = tid & 15, ty = tid >> 4;
  const float* Ap  = A  + (size_t)(row0 + am)*K + ak;
  const float* Bgp = Bg + (size_t)bk*N + col0 + bn;
  const float* Bup = Bu + (size_t)bk*N + col0 + bn;
  float accg[4][4], accu[4][4];
  #pragma unroll
  for (int i = 0; i < 4; ++i)
    #pragma unroll
    for (int j = 0; j < 4; ++j) { accg[i][j] = 0.0f; accu[i][j] = 0.0f; }
  for (int kt = 0; kt < K; kt += 16) {
    float4 av  = *(const float4*)(Ap + kt);
    float4 bgv = *(const float4*)(Bgp + (size_t)kt*N);
    float4 buv = *(const float4*)(Bup + (size_t)kt*N);
    As[ak+0][am] = av.x; As[ak+1][am] = av.y; As[ak+2][am] = av.z; As[ak+3][am] = av.w;
    *(float4*)&Bgs[bk][bn] = bgv;
    *(float4*)&Bus[bk][bn] = buv;
    __syncthreads();
    #pragma unroll
    for (int kk = 0; kk < 16; ++kk) {
      float4 a4 = *(const float4*)&As[kk][ty<<2];
      float4 g4 = *(const float4*)&Bgs[kk][tx<<2];
      float4 u4 = *(const float4*)&Bus[kk][tx<<2];
      float a[4] = {a4.x, a4.y, a4.z, a4.w};
      float gg[4] = {g4.x, g4.y, g4.z, g4.w};
      float uu[4] = {u4.x, u4.y, u4.z, u4.w};
      #pragma unroll
      for (int i = 0; i < 4; ++i)
        #pragma unroll
        for (int j = 0; j < 4; ++j) {
          accg[i][j] = fmaf(a[i], gg[j], accg[i][j]);
          accu[i][j] = fmaf(a[i], uu[j], accu[i][j]);
        }
    }
    __syncthreads();
  }
  #pragma unroll
  for (int i = 0; i < 4; ++i) {
    int r = row0 + (ty<<2) + i;
    #pragma unroll
    for (int j = 0; j < 4; ++j) {
      int c = col0 + (tx<<2) + j;
      float gv = accg[i][j];
      float s = gv * sigmoidf_(gv);
      C[(size_t)r*N + c] = s * accu[i][j];
    }
  }
}

// ---------------- down-proj GEMM + residual + gated scatter into d_out ----------------
__global__ __launch_bounds__(256) void k_down_scatter(const float* __restrict__ A,
    const float* __restrict__ Bm, const float* __restrict__ x2, const float* __restrict__ xsel,
    const float* __restrict__ gbuf, const int* __restrict__ idxb,
    float* __restrict__ outp, int M, int N, int K) {
  __shared__ float As[16][68];
  __shared__ float Bs[16][68];
  int tid = threadIdx.x;
  int bx = blockIdx.x, by = blockIdx.y;
  int row0 = by*64, col0 = bx*64;
  int am = tid >> 2, ak = (tid & 3) << 2;
  int bk = tid >> 4, bn = (tid & 15) << 2;
  int tx = tid & 15, ty = tid >> 4;
  const float* Ap = A + (size_t)(row0 + am)*K + ak;
  const float* Bp = Bm + (size_t)bk*N + col0 + bn;
  float acc[4][4];
  #pragma unroll
  for (int i = 0; i < 4; ++i)
    #pragma unroll
    for (int j = 0; j < 4; ++j) acc[i][j] = 0.0f;
  for (int kt = 0; kt < K; kt += 16) {
    float4 av = *(const float4*)(Ap + kt);
    float4 bv = *(const float4*)(Bp + (size_t)kt*N);
    As[ak+0][am] = av.x; As[ak+1][am] = av.y; As[ak+2][am] = av.z; As[ak+3][am] = av.w;
    *(float4*)&Bs[bk][bn] = bv;
    __syncthreads();
    #pragma unroll
    for (int kk = 0; kk < 16; ++kk) {
      float4 a4 = *(const float4*)&As[kk][ty<<2];
      float4 b4 = *(const float4*)&Bs[kk][tx<<2];
      float a[4] = {a4.x, a4.y, a4.z, a4.w};
      float bb[4] = {b4.x, b4.y, b4.z, b4.w};
      #pragma unroll
      for (int i = 0; i < 4; ++i)
        #pragma unroll
        for (int j = 0; j < 4; ++j) acc[i][j] = fmaf(a[i], bb[j], acc[i][j]);
    }
    __syncthreads();
  }
  #pragma unroll
  for (int i = 0; i < 4; ++i) {
    int r = row0 + (ty<<2) + i;           // selected row (b*KSEL + i)
    int b = r >> 10;
    int t = idxb[r];
    float gv = gbuf[r];
    size_t orow = ((size_t)(b*T_ + t))*D_;
    #pragma unroll
    for (int j = 0; j < 4; ++j) {
      int c = col0 + (tx<<2) + j;
      float xs  = xsel[(size_t)r*N + c];
      float x2v = x2[(size_t)r*N + c];
      float nv = xs + gv * (x2v + acc[i][j] - xs);
      outp[orow + c] = nv;
    }
  }
}

// ---------------- flash-style causal attention over selected tokens ----------------
__global__ __launch_bounds__(256) void k_attn(const float* __restrict__ Q,
    const float* __restrict__ Km, const float* __restrict__ V, float* __restrict__ O) {
  int qt = blockIdx.x;   // 0..15
  int h  = blockIdx.y;   // 0..15
  int b  = blockIdx.z;   // 0..1
  __shared__ float Qs[64][132];
  __shared__ float KVs[64][132];
  __shared__ float Ss[64][68];
  __shared__ float mrow[64], lrow[64];
  int tid = threadIdx.x;
  size_t base = ((size_t)b*KSEL)*D_ + (size_t)h*HD_;
  #pragma unroll
  for (int i = 0; i < 8; ++i) {
    int f = tid + i*256; int r = f >> 5; int c = (f & 31) << 2;
    *(float4*)&Qs[r][c] = *(const float4*)(Q + base + (size_t)(qt*64 + r)*D_ + c);
  }
  if (tid < 64) { mrow[tid] = -1e30f; lrow[tid] = 0.0f; }
  float acc[32];
  #pragma unroll
  for (int i = 0; i < 32; ++i) acc[i] = 0.0f;
  int tx = tid & 15, ty = tid >> 4;
  int rr = tid >> 2, seg = (tid & 3) * 16;
  int g4 = tid & 3;
  int colA = g4 * 32;
  __syncthreads();
  const float sc = 0.08838834764831845f;   // HD^-0.5
  for (int kt = 0; kt <= qt; ++kt) {
    #pragma unroll
    for (int i = 0; i < 8; ++i) {
      int f = tid + i*256; int r = f >> 5; int c = (f & 31) << 2;
      *(float4*)&KVs[r][c] = *(const float4*)(Km + base + (size_t)(kt*64 + r)*D_ + c);
    }
    __syncthreads();
    float s[4][4];
    #pragma unroll
    for (int i = 0; i < 4; ++i)
      #pragma unroll
      for (int j = 0; j < 4; ++j) s[i][j] = 0.0f;
    #pragma unroll 4
    for (int d = 0; d < HD_; d += 4) {
      float4 qv[4], kv[4];
      #pragma unroll
      for (int i = 0; i < 4; ++i) qv[i] = *(const float4*)&Qs[ty + 16*i][d];
      #pragma unroll
      for (int j = 0; j < 4; ++j) kv[j] = *(const float4*)&KVs[tx + 16*j][d];
      #pragma unroll
      for (int i = 0; i < 4; ++i)
        #pragma unroll
        for (int j = 0; j < 4; ++j) {
          s[i][j] = fmaf(qv[i].x, kv[j].x, s[i][j]);
          s[i][j] = fmaf(qv[i].y, kv[j].y, s[i][j]);
          s[i][j] = fmaf(qv[i].z, kv[j].z, s[i][j]);
          s[i][j] = fmaf(qv[i].w, kv[j].w, s[i][j]);
        }
    }
    #pragma unroll
    for (int i = 0; i < 4; ++i)
      #pragma unroll
      for (int j = 0; j < 4; ++j) {
        int qpos = qt*64 + ty + 16*i, kpos = kt*64 + tx + 16*j;
        float v = s[i][j] * sc;
        if (kpos > qpos) v = -1e9f;
        Ss[ty + 16*i][tx + 16*j] = v;
      }
    __syncthreads();
    // row stats: 4 lanes per row
    float mold = mrow[rr];
    float tmax = -1e30f;
    for (int c2 = 0; c2 < 16; ++c2) tmax = fmaxf(tmax, Ss[rr][seg + c2]);
    tmax = fmaxf(tmax, __shfl_xor(tmax, 1));
    tmax = fmaxf(tmax, __shfl_xor(tmax, 2));
    float mnew = fmaxf(mold, tmax);
    float psum = 0.0f;
    for (int c2 = 0; c2 < 16; ++c2) {
      float p = expf(Ss[rr][seg + c2] - mnew);
      Ss[rr][seg + c2] = p;
      psum += p;
    }
    psum += __shfl_xor(psum, 1);
    psum += __shfl_xor(psum, 2);
    float scale = expf(mold - mnew);
    if (g4 == 0) { mrow[rr] = mnew; lrow[rr] = lrow[rr]*scale + psum; }
    __syncthreads();
    // load V over K tile
    #pragma unroll
    for (int i = 0; i < 8; ++i) {
      int f = tid + i*256; int r = f >> 5; int c = (f & 31) << 2;
      *(float4*)&KVs[r][c] = *(const float4*)(V + base + (size_t)(kt*64 + r)*D_ + c);
    }
    #pragma unroll
    for (int i = 0; i < 32; ++i) acc[i] *= scale;
    __syncthreads();
    for (int j = 0; j < 64; ++j) {
      float p = Ss[rr][j];
      #pragma unroll
      for (int c4r = 0; c4r < 8; ++c4r) {
        int c4 = (c4r + g4*2) & 7;                       // rotate to avoid bank conflicts
        float4 vv = *(const float4*)&KVs[j][colA + c4*4];
        acc[c4*4+0] = fmaf(p, vv.x, acc[c4*4+0]);
        acc[c4*4+1] = fmaf(p, vv.y, acc[c4*4+1]);
        acc[c4*4+2] = fmaf(p, vv.z, acc[c4*4+2]);
        acc[c4*4+3] = fmaf(p, vv.w, acc[c4*4+3]);
      }
    }
    __syncthreads();
  }
  float invl = 1.0f / lrow[rr];
  float* orow = O + base + (size_t)(qt*64 + rr)*D_ + colA;
  #pragma unroll
  for (int c4 = 0; c4 < 8; ++c4) {
    float4 ov;
    ov.x = acc[c4*4+0]*invl; ov.y = acc[c4*4+1]*invl;
    ov.z = acc[c4*4+2]*invl; ov.w = acc[c4*4+3]*invl;
    *(float4*)(orow + c4*4) = ov;
  }
}

// ---------------- predictor logits: wave per row, h[8192,512] . fc2_w ----------------
__global__ __launch_bounds__(256) void k_pred_logits(const float* __restrict__ h,
      const float* __restrict__ fc2w, const float* __restrict__ fc2b, float* __restrict__ plog) {
  int wid = threadIdx.x >> 6, lane = threadIdx.x & 63;
  int row = blockIdx.x*4 + wid;
  const float4* hr = (const float4*)(h + (size_t)row*512);
  const float4* w4 = (const float4*)fc2w;
  float acc = 0.0f;
  #pragma unroll
  for (int i = lane; i < 128; i += 64) {
    float4 a = hr[i], w = w4[i];
    acc += a.x*w.x + a.y*w.y + a.z*w.z + a.w*w.w;
  }
  for (int off = 32; off > 0; off >>= 1) acc += __shfl_down(acc, off);
  if (lane == 0) plog[row] = acc + fc2b[0];
}

extern "C" void kernel_launch(void* const* d_in, const int* in_sizes, int n_in,
                              void* d_out, int out_size, void* d_ws, size_t ws_size,
                              hipStream_t stream) {
  const float* hs      = (const float*)d_in[0];
  const float* router_w= (const float*)d_in[1];
  const float* fc1_w   = (const float*)d_in[2];
  const float* fc1_b   = (const float*)d_in[3];
  const float* fc2_w   = (const float*)d_in[4];
  const float* fc2_b   = (const float*)d_in[5];
  const float* ln1_w   = (const float*)d_in[6];
  const float* ln2_w   = (const float*)d_in[7];
  const float* wq      = (const float*)d_in[8];
  const float* bq      = (const float*)d_in[9];
  const float* wk      = (const float*)d_in[10];
  const float* bk      = (const float*)d_in[11];
  const float* wv      = (const float*)d_in[12];
  const float* bv      = (const float*)d_in[13];
  const float* wo      = (const float*)d_in[14];
  const float* w_gate  = (const float*)d_in[15];
  const float* w_up    = (const float*)d_in[16];
  const float* w_down  = (const float*)d_in[17];
  float* out = (float*)d_out;

  float* ws = (float*)d_ws;
  float* logits = ws;                       // 8192
  float* flags  = ws + 8192;                // 8192
  int*   idxb   = (int*)(ws + 16384);       // 2048
  float* gbuf   = ws + 18432;               // 2048
  float* plog   = ws + 20480;               // 8192
  float* bufA   = ws + 32768;               // x_sel   [MSEL, D]
  float* bufB   = bufA + 4194304;           // xa / xm [MSEL, D]
  float* bufC   = bufB + 4194304;           // q ; later inter (spans C..F) ; later h_pred
  float* bufD   = bufC + 4194304;           // k
  float* bufE   = bufD + 4194304;           // v
  float* bufF   = bufE + 4194304;           // attn out
  float* bufG   = bufF + 4194304;           // x2
  float* inter  = bufC;                     // [MSEL, FF] = 64MB spans C..F
  float* hbuf   = bufC;                     // predictor h [NTOK, 512], after inter consumed

  // 1. router
  k_router_logits<<<NTOK, 256, 0, stream>>>(hs, router_w, logits);
  k_topk<<<B_, 1024, 0, stream>>>(logits, idxb, gbuf, flags);
  k_router_loss<<<1, 256, 0, stream>>>(logits, flags, out + (size_t)NTOK*D_);

  // 2. base copy of hidden states into output
  k_copy<<<2048, 256, 0, stream>>>((const float4*)hs, (float4*)out, NTOK*D_/4);

  // 3. gather + rmsnorm1
  k_gather_rms<<<MSEL, 256, 0, stream>>>(hs, idxb, ln1_w, bufA, bufB);

  // 4. qkv projections
  dim3 gqkv(D_/64, MSEL/64);
  k_gemm<0><<<gqkv, 256, 0, stream>>>(bufB, wq, bq, nullptr, bufC, MSEL, D_, D_);
  k_gemm<0><<<gqkv, 256, 0, stream>>>(bufB, wk, bk, nullptr, bufD, MSEL, D_, D_);
  k_gemm<0><<<gqkv, 256, 0, stream>>>(bufB, wv, bv, nullptr, bufE, MSEL, D_, D_);

  // 5. attention
  dim3 gattn(KSEL/64, H_, B_);
  k_attn<<<gattn, 256, 0, stream>>>(bufC, bufD, bufE, bufF);

  // 6. o-proj + residual -> x2
  k_gemm<1><<<gqkv, 256, 0, stream>>>(bufF, wo, nullptr, bufA, bufG, MSEL, D_, D_);

  // 7. rmsnorm2
  k_rms<<<MSEL, 256, 0, stream>>>(bufG, ln2_w, bufB);

  // 8. gate/up fused -> inter
  dim3 gmlp(FF_/64, MSEL/64);
  k_dualgemm<<<gmlp, 256, 0, stream>>>(bufB, w_gate, w_up, inter, MSEL, FF_, D_);

  // 9. down proj + residual + gated scatter
  dim3 gdown(D_/64, MSEL/64);
  k_down_scatter<<<gdown, 256, 0, stream>>>(inter, w_down, bufG, bufA, gbuf, idxb,
                                            out, MSEL, D_, FF_);

  // 10. predictor (detached): h = gelu(hs@fc1+b) ; plog = h.fc2+b ; bce
  dim3 gpred(512/64, NTOK/64);
  k_gemm<2><<<gpred, 256, 0, stream>>>(hs, fc1_w, fc1_b, nullptr, hbuf, NTOK, 512, D_);
  k_pred_logits<<<NTOK/4, 256, 0, stream>>>(hbuf, fc2_w, fc2_b, plog);
  k_bce<<<1, 256, 0, stream>>>(plog, flags, out + (size_t)NTOK*D_ + 2);
}

// Round 3
// 4663.805 us; speedup vs baseline: 3.6675x; 3.6675x over previous
//
#include <hip/hip_runtime.h>
#include <cstdint>
#include <cstddef>

#define D_    2048
#define T_    4096
#define B_    2
#define KSEL  1024
#define FF_   8192
#define NTOK  (B_*T_)      // 8192
#define MSEL  (B_*KSEL)    // 2048
#define HD_   128
#define H_    16

__device__ __forceinline__ float sigmoidf_(float x){ return 1.0f/(1.0f+expf(-x)); }
__device__ __forceinline__ float geluf_(float x){ return 0.5f*x*(1.0f+erff(x*0.70710678118654752440f)); }

// ---------------- router logits: logits[row] = hs[row,:] . router_w (fp64 accum) ----------------
__global__ __launch_bounds__(256) void k_router_logits(const float* __restrict__ hs,
        const float* __restrict__ rw, float* __restrict__ logits) {
  int row = blockIdx.x;
  const float4* x = (const float4*)(hs + (size_t)row * D_);
  const float4* w = (const float4*)rw;
  int tid = threadIdx.x;
  double acc = 0.0;
  for (int i = tid; i < D_/4; i += 256) {
    float4 a = x[i]; float4 b = w[i];
    acc += (double)a.x*b.x + (double)a.y*b.y + (double)a.z*b.z + (double)a.w*b.w;
  }
  __shared__ double red[256];
  red[tid] = acc; __syncthreads();
  for (int s = 128; s > 0; s >>= 1) { if (tid < s) red[tid] += red[tid+s]; __syncthreads(); }
  if (tid == 0) logits[row] = (float)red[0];
}

// ---------------- top-k via bitonic sort of packed keys (desc value, tie -> lower idx) ----------
__global__ __launch_bounds__(1024) void k_topk(const float* __restrict__ logits,
      int* __restrict__ idx_out, float* __restrict__ g_out, float* __restrict__ flags) {
  int b = blockIdx.x;
  int tid = threadIdx.x;
  __shared__ unsigned long long keys[T_];
  for (int i = tid; i < T_; i += 1024) {
    float v = logits[b*T_ + i];
    unsigned u = __float_as_uint(v);
    unsigned s = (u & 0x80000000u) ? ~u : (u | 0x80000000u);
    keys[i] = ((unsigned long long)s << 32) | (unsigned long long)(0xFFFFFFFFu - (unsigned)i);
    flags[b*T_ + i] = 0.0f;
  }
  __syncthreads();
  for (int size = 2; size <= T_; size <<= 1) {
    for (int stride = size >> 1; stride > 0; stride >>= 1) {
      for (int i = tid; i < T_; i += 1024) {
        int l = i ^ stride;
        if (l > i) {
          unsigned long long a = keys[i], c = keys[l];
          bool up = ((i & size) == 0);
          bool sw = up ? (a < c) : (a > c);   // descending overall
          if (sw) { keys[i] = c; keys[l] = a; }
        }
      }
      __syncthreads();
    }
  }
  if (tid < KSEL) {
    unsigned long long kk = keys[tid];
    unsigned s = (unsigned)(kk >> 32);
    unsigned u = (s & 0x80000000u) ? (s & 0x7FFFFFFFu) : ~s;
    float v = __uint_as_float(u);
    int t = (int)(0xFFFFFFFFu - (unsigned)(kk & 0xFFFFFFFFull));
    idx_out[b*KSEL + tid] = t;
    g_out[b*KSEL + tid] = sigmoidf_(v);
    flags[b*T_ + t] = 1.0f;
  }
}

// ---------------- router losses (bce + z), single block ----------------
__global__ __launch_bounds__(256) void k_router_loss(const float* __restrict__ logits,
      const float* __restrict__ flags, float* __restrict__ outp) {
  int tid = threadIdx.x;
  double bce = 0.0, z = 0.0;
  for (int i = tid; i < NTOK; i += 256) {
    float x = logits[i], y = flags[i];
    bce += (double)(fmaxf(x, 0.0f) - x*y + log1pf(expf(-fabsf(x))));
    z   += (double)x * (double)x;
  }
  __shared__ double r1[256], r2[256];
  r1[tid] = bce; r2[tid] = z; __syncthreads();
  for (int s = 128; s > 0; s >>= 1) {
    if (tid < s) { r1[tid] += r1[tid+s]; r2[tid] += r2[tid+s]; }
    __syncthreads();
  }
  if (tid == 0) {
    outp[0] = (float)(r1[0] / (double)NTOK);
    outp[1] = (float)(r2[0] / (double)NTOK * 1e-4);
  }
}

// ---------------- generic BCE (predictor loss) ----------------
__global__ __launch_bounds__(256) void k_bce(const float* __restrict__ x,
      const float* __restrict__ y, float* __restrict__ outp) {
  int tid = threadIdx.x;
  double bce = 0.0;
  for (int i = tid; i < NTOK; i += 256) {
    float xv = x[i], yv = y[i];
    bce += (double)(fmaxf(xv, 0.0f) - xv*yv + log1pf(expf(-fabsf(xv))));
  }
  __shared__ double r1[256];
  r1[tid] = bce; __syncthreads();
  for (int s = 128; s > 0; s >>= 1) { if (tid < s) r1[tid] += r1[tid+s]; __syncthreads(); }
  if (tid == 0) outp[0] = (float)(r1[0] / (double)NTOK);
}

// ---------------- copy hidden_states -> d_out ----------------
__global__ __launch_bounds__(256) void k_copy(const float4* __restrict__ src,
      float4* __restrict__ dst, int n4) {
  int i = blockIdx.x*256 + threadIdx.x;
  int stride = gridDim.x*256;
  for (; i < n4; i += stride) dst[i] = src[i];
}

// ---------------- gather selected rows + RMSNorm(ln1) ----------------
__global__ __launch_bounds__(256) void k_gather_rms(const float* __restrict__ hs,
      const int* __restrict__ idx, const float* __restrict__ w,
      float* __restrict__ xsel, float* __restrict__ xa) {
  int row = blockIdx.x;               // 0..MSEL-1
  int b = row >> 10;
  int t = idx[row];
  const float4* src = (const float4*)(hs + ((size_t)(b*T_ + t)) * D_);
  float4* xs4 = (float4*)(xsel + (size_t)row*D_);
  float4* xa4 = (float4*)(xa  + (size_t)row*D_);
  const float4* w4 = (const float4*)w;
  int tid = threadIdx.x;
  float4 loc[2];
  double ss = 0.0;
  #pragma unroll
  for (int j = 0; j < 2; ++j) {
    float4 v = src[tid + j*256];
    loc[j] = v;
    ss += (double)v.x*v.x + (double)v.y*v.y + (double)v.z*v.z + (double)v.w*v.w;
  }
  __shared__ double red[256];
  red[tid] = ss; __syncthreads();
  for (int s = 128; s > 0; s >>= 1) { if (tid < s) red[tid] += red[tid+s]; __syncthreads(); }
  float rms = (float)(1.0 / sqrt(red[0] / (double)D_ + 1e-6));
  #pragma unroll
  for (int j = 0; j < 2; ++j) {
    float4 v = loc[j];
    float4 ww = w4[tid + j*256];
    xs4[tid + j*256] = v;
    float4 o; o.x = v.x*rms*ww.x; o.y = v.y*rms*ww.y; o.z = v.z*rms*ww.z; o.w = v.w*rms*ww.w;
    xa4[tid + j*256] = o;
  }
}

// ---------------- plain RMSNorm ----------------
__global__ __launch_bounds__(256) void k_rms(const float* __restrict__ x,
      const float* __restrict__ w, float* __restrict__ y) {
  int row = blockIdx.x;
  const float4* xr = (const float4*)(x + (size_t)row*D_);
  float4* yr = (float4*)(y + (size_t)row*D_);
  const float4* w4 = (const float4*)w;
  int tid = threadIdx.x;
  float4 loc[2];
  double ss = 0.0;
  #pragma unroll
  for (int j = 0; j < 2; ++j) {
    float4 v = xr[tid + j*256];
    loc[j] = v;
    ss += (double)v.x*v.x + (double)v.y*v.y + (double)v.z*v.z + (double)v.w*v.w;
  }
  __shared__ double red[256];
  red[tid] = ss; __syncthreads();
  for (int s = 128; s > 0; s >>= 1) { if (tid < s) red[tid] += red[tid+s]; __syncthreads(); }
  float rms = (float)(1.0 / sqrt(red[0] / (double)D_ + 1e-6));
  #pragma unroll
  for (int j = 0; j < 2; ++j) {
    float4 v = loc[j];
    float4 ww = w4[tid + j*256];
    float4 o; o.x = v.x*rms*ww.x; o.y = v.y*rms*ww.y; o.z = v.z*rms*ww.z; o.w = v.w*rms*ww.w;
    yr[tid + j*256] = o;
  }
}

// ---------------- generic 64x64 fp32 GEMM, MODE: 0=+bias, 1=+residual, 2=gelu(+bias) ----------
template<int MODE>
__global__ __launch_bounds__(256) void k_gemm(const float* __restrict__ A, const float* __restrict__ Bm,
    const float* __restrict__ bias, const float* __restrict__ res, float* __restrict__ C,
    int M, int N, int K) {
  __shared__ float As[16][68];
  __shared__ float Bs[16][68];
  int tid = threadIdx.x;
  int bx = blockIdx.x, by = blockIdx.y;
  int row0 = by*64, col0 = bx*64;
  int am = tid >> 2, ak = (tid & 3) << 2;   // A stage: row am, k ak..ak+3
  int bk = tid >> 4, bn = (tid & 15) << 2;  // B stage: k bk, col bn..bn+3
  int tx = tid & 15, ty = tid >> 4;
  const float* Ap = A + (size_t)(row0 + am)*K + ak;
  const float* Bp = Bm + (size_t)bk*N + col0 + bn;
  float acc[4][4];
  #pragma unroll
  for (int i = 0; i < 4; ++i)
    #pragma unroll
    for (int j = 0; j < 4; ++j) acc[i][j] = 0.0f;
  for (int kt = 0; kt < K; kt += 16) {
    float4 av = *(const float4*)(Ap + kt);
    float4 bv = *(const float4*)(Bp + (size_t)kt*N);
    As[ak+0][am] = av.x; As[ak+1][am] = av.y; As[ak+2][am] = av.z; As[ak+3][am] = av.w;
    *(float4*)&Bs[bk][bn] = bv;
    __syncthreads();
    #pragma unroll
    for (int kk = 0; kk < 16; ++kk) {
      float4 a4 = *(const float4*)&As[kk][ty<<2];
      float4 b4 = *(const float4*)&Bs[kk][tx<<2];
      float a[4] = {a4.x, a4.y, a4.z, a4.w};
      float bb[4] = {b4.x, b4.y, b4.z, b4.w};
      #pragma unroll
      for (int i = 0; i < 4; ++i)
        #pragma unroll
        for (int j = 0; j < 4; ++j) acc[i][j] = fmaf(a[i], bb[j], acc[i][j]);
    }
    __syncthreads();
  }
  #pragma unroll
  for (int i = 0; i < 4; ++i) {
    int r = row0 + (ty<<2) + i;
    #pragma unroll
    for (int j = 0; j < 4; ++j) {
      int c = col0 + (tx<<2) + j;
      float v = acc[i][j];
      if (MODE == 0) v += bias[c];
      if (MODE == 1) v += res[(size_t)r*N + c];
      if (MODE == 2) { v += bias[c]; v = geluf_(v); }
      C[(size_t)r*N + c] = v;
    }
  }
}

// ---------------- dual GEMM for gate/up, epilogue silu(g)*u ----------------
__global__ __launch_bounds__(256) void k_dualgemm(const float* __restrict__ A,
    const float* __restrict__ Bg, const float* __restrict__ Bu,
    float* __restrict__ C, int M, int N, int K) {
  __shared__ float As[16][68];
  __shared__ float Bgs[16][68];
  __shared__ float Bus[16][68];
  int tid = threadIdx.x;
  int bx = blockIdx.x, by = blockIdx.y;
  int row0 = by*64, col0 = bx*64;
  int am = tid >> 2, ak = (tid & 3) << 2;
  int bk = tid >> 4, bn = (tid & 15) << 2;
  int tx = tid & 15, ty = tid >> 4;
  const float* Ap  = A  + (size_t)(row0 + am)*K + ak;
  const float* Bgp = Bg + (size_t)bk*N + col0 + bn;
  const float* Bup = Bu + (size_t)bk*N + col0 + bn;
  float accg[4][4], accu[4][4];
  #pragma unroll
  for (int i = 0; i < 4; ++i)
    #pragma unroll
    for (int j = 0; j < 4; ++j) { accg[i][j] = 0.0f; accu[i][j] = 0.0f; }
  for (int kt = 0; kt < K; kt += 16) {
    float4 av  = *(const float4*)(Ap + kt);
    float4 bgv = *(const float4*)(Bgp + (size_t)kt*N);
    float4 buv = *(const float4*)(Bup + (size_t)kt*N);
    As[ak+0][am] = av.x; As[ak+1][am] = av.y; As[ak+2][am] = av.z; As[ak+3][am] = av.w;
    *(float4*)&Bgs[bk][bn] = bgv;
    *(float4*)&Bus[bk][bn] = buv;
    __syncthreads();
    #pragma unroll
    for (int kk = 0; kk < 16; ++kk) {
      float4 a4 = *(const float4*)&As[kk][ty<<2];
      float4 g4 = *(const float4*)&Bgs[kk][tx<<2];
      float4 u4 = *(const float4*)&Bus[kk][tx<<2];
      float a[4] = {a4.x, a4.y, a4.z, a4.w};
      float gg[4] = {g4.x, g4.y, g4.z, g4.w};
      float uu[4] = {u4.x, u4.y, u4.z, u4.w};
      #pragma unroll
      for (int i = 0; i < 4; ++i)
        #pragma unroll
        for (int j = 0; j < 4; ++j) {
          accg[i][j] = fmaf(a[i], gg[j], accg[i][j]);
          accu[i][j] = fmaf(a[i], uu[j], accu[i][j]);
        }
    }
    __syncthreads();
  }
  #pragma unroll
  for (int i = 0; i < 4; ++i) {
    int r = row0 + (ty<<2) + i;
    #pragma unroll
    for (int j = 0; j < 4; ++j) {
      int c = col0 + (tx<<2) + j;
      float gv = accg[i][j];
      float s = gv * sigmoidf_(gv);
      C[(size_t)r*N + c] = s * accu[i][j];
    }
  }
}

// ---------------- down-proj GEMM + residual + gated scatter into d_out ----------------
__global__ __launch_bounds__(256) void k_down_scatter(const float* __restrict__ A,
    const float* __restrict__ Bm, const float* __restrict__ x2, const float* __restrict__ xsel,
    const float* __restrict__ gbuf, const int* __restrict__ idxb,
    float* __restrict__ outp, int M, int N, int K) {
  __shared__ float As[16][68];
  __shared__ float Bs[16][68];
  int tid = threadIdx.x;
  int bx = blockIdx.x, by = blockIdx.y;
  int row0 = by*64, col0 = bx*64;
  int am = tid >> 2, ak = (tid & 3) << 2;
  int bk = tid >> 4, bn = (tid & 15) << 2;
  int tx = tid & 15, ty = tid >> 4;
  const float* Ap = A + (size_t)(row0 + am)*K + ak;
  const float* Bp = Bm + (size_t)bk*N + col0 + bn;
  float acc[4][4];
  #pragma unroll
  for (int i = 0; i < 4; ++i)
    #pragma unroll
    for (int j = 0; j < 4; ++j) acc[i][j] = 0.0f;
  for (int kt = 0; kt < K; kt += 16) {
    float4 av = *(const float4*)(Ap + kt);
    float4 bv = *(const float4*)(Bp + (size_t)kt*N);
    As[ak+0][am] = av.x; As[ak+1][am] = av.y; As[ak+2][am] = av.z; As[ak+3][am] = av.w;
    *(float4*)&Bs[bk][bn] = bv;
    __syncthreads();
    #pragma unroll
    for (int kk = 0; kk < 16; ++kk) {
      float4 a4 = *(const float4*)&As[kk][ty<<2];
      float4 b4 = *(const float4*)&Bs[kk][tx<<2];
      float a[4] = {a4.x, a4.y, a4.z, a4.w};
      float bb[4] = {b4.x, b4.y, b4.z, b4.w};
      #pragma unroll
      for (int i = 0; i < 4; ++i)
        #pragma unroll
        for (int j = 0; j < 4; ++j) acc[i][j] = fmaf(a[i], bb[j], acc[i][j]);
    }
    __syncthreads();
  }
  #pragma unroll
  for (int i = 0; i < 4; ++i) {
    int r = row0 + (ty<<2) + i;           // selected row (b*KSEL + i)
    int b = r >> 10;
    int t = idxb[r];
    float gv = gbuf[r];
    size_t orow = ((size_t)(b*T_ + t))*D_;
    #pragma unroll
    for (int j = 0; j < 4; ++j) {
      int c = col0 + (tx<<2) + j;
      float xs  = xsel[(size_t)r*N + c];
      float x2v = x2[(size_t)r*N + c];
      float nv = xs + gv * (x2v + acc[i][j] - xs);
      outp[orow + c] = nv;
    }
  }
}

// ---------------- flash-style causal attention over selected tokens ----------------
// FIX vs round 0: PV accumulator indexing is now STATIC (was runtime-rotated ->
// acc[] lived in scratch, 12.6ms). Bank conflicts from the 32-column lane groups are
// instead solved by swizzling the V staging: physical col = c + (c>>5)*4, so the 4
// lane groups read disjoint bank quads. K phase stages linearly (2-way alias = free).
__global__ __launch_bounds__(256) void k_attn(const float* __restrict__ Q,
    const float* __restrict__ Km, const float* __restrict__ V, float* __restrict__ O) {
  int qt = gridDim.x - 1 - blockIdx.x;   // heavy tiles first (load balance)
  int h  = blockIdx.y;   // 0..15
  int b  = blockIdx.z;   // 0..1
  __shared__ float Qs[64][132];
  __shared__ float KVs[64][140];
  __shared__ float Ss[64][68];
  __shared__ float mrow[64], lrow[64];
  int tid = threadIdx.x;
  size_t base = ((size_t)b*KSEL)*D_ + (size_t)h*HD_;
  #pragma unroll
  for (int i = 0; i < 8; ++i) {
    int f = tid + i*256; int r = f >> 5; int c = (f & 31) << 2;
    *(float4*)&Qs[r][c] = *(const float4*)(Q + base + (size_t)(qt*64 + r)*D_ + c);
  }
  if (tid < 64) { mrow[tid] = -1e30f; lrow[tid] = 0.0f; }
  float acc[32];
  #pragma unroll
  for (int i = 0; i < 32; ++i) acc[i] = 0.0f;
  int tx = tid & 15, ty = tid >> 4;
  int rr = tid >> 2, seg = (tid & 3) * 16;
  int g4 = tid & 3;
  int colA = g4 * 32;
  int vbase = g4 * 36;                   // swizzled base for V reads (32 + 4 shift)
  __syncthreads();
  const float sc = 0.08838834764831845f;   // HD^-0.5
  for (int kt = 0; kt <= qt; ++kt) {
    #pragma unroll
    for (int i = 0; i < 8; ++i) {
      int f = tid + i*256; int r = f >> 5; int c = (f & 31) << 2;
      *(float4*)&KVs[r][c] = *(const float4*)(Km + base + (size_t)(kt*64 + r)*D_ + c);
    }
    __syncthreads();
    float s[4][4];
    #pragma unroll
    for (int i = 0; i < 4; ++i)
      #pragma unroll
      for (int j = 0; j < 4; ++j) s[i][j] = 0.0f;
    #pragma unroll 4
    for (int d = 0; d < HD_; d += 4) {
      float4 qv[4], kv[4];
      #pragma unroll
      for (int i = 0; i < 4; ++i) qv[i] = *(const float4*)&Qs[ty + 16*i][d];
      #pragma unroll
      for (int j = 0; j < 4; ++j) kv[j] = *(const float4*)&KVs[tx + 16*j][d];
      #pragma unroll
      for (int i = 0; i < 4; ++i)
        #pragma unroll
        for (int j = 0; j < 4; ++j) {
          s[i][j] = fmaf(qv[i].x, kv[j].x, s[i][j]);
          s[i][j] = fmaf(qv[i].y, kv[j].y, s[i][j]);
          s[i][j] = fmaf(qv[i].z, kv[j].z, s[i][j]);
          s[i][j] = fmaf(qv[i].w, kv[j].w, s[i][j]);
        }
    }
    #pragma unroll
    for (int i = 0; i < 4; ++i)
      #pragma unroll
      for (int j = 0; j < 4; ++j) {
        int qpos = qt*64 + ty + 16*i, kpos = kt*64 + tx + 16*j;
        float v = s[i][j] * sc;
        if (kpos > qpos) v = -1e9f;
        Ss[ty + 16*i][tx + 16*j] = v;
      }
    __syncthreads();
    // row stats: 4 lanes per row
    float mold = mrow[rr];
    float tmax = -1e30f;
    for (int c2 = 0; c2 < 16; ++c2) tmax = fmaxf(tmax, Ss[rr][seg + c2]);
    tmax = fmaxf(tmax, __shfl_xor(tmax, 1));
    tmax = fmaxf(tmax, __shfl_xor(tmax, 2));
    float mnew = fmaxf(mold, tmax);
    float psum = 0.0f;
    for (int c2 = 0; c2 < 16; ++c2) {
      float p = expf(Ss[rr][seg + c2] - mnew);
      Ss[rr][seg + c2] = p;
      psum += p;
    }
    psum += __shfl_xor(psum, 1);
    psum += __shfl_xor(psum, 2);
    float scale = expf(mold - mnew);
    if (g4 == 0) { mrow[rr] = mnew; lrow[rr] = lrow[rr]*scale + psum; }
    __syncthreads();
    // load V over K tile, column-swizzled: logical col c -> physical c + (c>>5)*4
    #pragma unroll
    for (int i = 0; i < 8; ++i) {
      int f = tid + i*256; int r = f >> 5; int c = (f & 31) << 2;
      int pc = c + ((c >> 5) << 2);
      *(float4*)&KVs[r][pc] = *(const float4*)(V + base + (size_t)(kt*64 + r)*D_ + c);
    }
    #pragma unroll
    for (int i = 0; i < 32; ++i) acc[i] *= scale;
    __syncthreads();
    for (int j = 0; j < 64; ++j) {
      float p = Ss[rr][j];
      #pragma unroll
      for (int c4 = 0; c4 < 8; ++c4) {            // STATIC index -> acc stays in VGPRs
        float4 vv = *(const float4*)&KVs[j][vbase + c4*4];
        acc[c4*4+0] = fmaf(p, vv.x, acc[c4*4+0]);
        acc[c4*4+1] = fmaf(p, vv.y, acc[c4*4+1]);
        acc[c4*4+2] = fmaf(p, vv.z, acc[c4*4+2]);
        acc[c4*4+3] = fmaf(p, vv.w, acc[c4*4+3]);
      }
    }
    __syncthreads();
  }
  float invl = 1.0f / lrow[rr];
  float* orow = O + base + (size_t)(qt*64 + rr)*D_ + colA;
  #pragma unroll
  for (int c4 = 0; c4 < 8; ++c4) {
    float4 ov;
    ov.x = acc[c4*4+0]*invl; ov.y = acc[c4*4+1]*invl;
    ov.z = acc[c4*4+2]*invl; ov.w = acc[c4*4+3]*invl;
    *(float4*)(orow + c4*4) = ov;
  }
}

// ---------------- predictor logits: wave per row, h[8192,512] . fc2_w ----------------
__global__ __launch_bounds__(256) void k_pred_logits(const float* __restrict__ h,
      const float* __restrict__ fc2w, const float* __restrict__ fc2b, float* __restrict__ plog) {
  int wid = threadIdx.x >> 6, lane = threadIdx.x & 63;
  int row = blockIdx.x*4 + wid;
  const float4* hr = (const float4*)(h + (size_t)row*512);
  const float4* w4 = (const float4*)fc2w;
  float acc = 0.0f;
  #pragma unroll
  for (int i = lane; i < 128; i += 64) {
    float4 a = hr[i], w = w4[i];
    acc += a.x*w.x + a.y*w.y + a.z*w.z + a.w*w.w;
  }
  for (int off = 32; off > 0; off >>= 1) acc += __shfl_down(acc, off);
  if (lane == 0) plog[row] = acc + fc2b[0];
}

extern "C" void kernel_launch(void* const* d_in, const int* in_sizes, int n_in,
                              void* d_out, int out_size, void* d_ws, size_t ws_size,
                              hipStream_t stream) {
  const float* hs      = (const float*)d_in[0];
  const float* router_w= (const float*)d_in[1];
  const float* fc1_w   = (const float*)d_in[2];
  const float* fc1_b   = (const float*)d_in[3];
  const float* fc2_w   = (const float*)d_in[4];
  const float* fc2_b   = (const float*)d_in[5];
  const float* ln1_w   = (const float*)d_in[6];
  const float* ln2_w   = (const float*)d_in[7];
  const float* wq      = (const float*)d_in[8];
  const float* bq      = (const float*)d_in[9];
  const float* wk      = (const float*)d_in[10];
  const float* bk      = (const float*)d_in[11];
  const float* wv      = (const float*)d_in[12];
  const float* bv      = (const float*)d_in[13];
  const float* wo      = (const float*)d_in[14];
  const float* w_gate  = (const float*)d_in[15];
  const float* w_up    = (const float*)d_in[16];
  const float* w_down  = (const float*)d_in[17];
  float* out = (float*)d_out;

  float* ws = (float*)d_ws;
  float* logits = ws;                       // 8192
  float* flags  = ws + 8192;                // 8192
  int*   idxb   = (int*)(ws + 16384);       // 2048
  float* gbuf   = ws + 18432;               // 2048
  float* plog   = ws + 20480;               // 8192
  float* bufA   = ws + 32768;               // x_sel   [MSEL, D]
  float* bufB   = bufA + 4194304;           // xa / xm [MSEL, D]
  float* bufC   = bufB + 4194304;           // q ; later inter (spans C..F) ; later h_pred
  float* bufD   = bufC + 4194304;           // k
  float* bufE   = bufD + 4194304;           // v
  float* bufF   = bufE + 4194304;           // attn out
  float* bufG   = bufF + 4194304;           // x2
  float* inter  = bufC;                     // [MSEL, FF] = 64MB spans C..F
  float* hbuf   = bufC;                     // predictor h [NTOK, 512], after inter consumed

  // 1. router
  k_router_logits<<<NTOK, 256, 0, stream>>>(hs, router_w, logits);
  k_topk<<<B_, 1024, 0, stream>>>(logits, idxb, gbuf, flags);
  k_router_loss<<<1, 256, 0, stream>>>(logits, flags, out + (size_t)NTOK*D_);

  // 2. base copy of hidden states into output
  k_copy<<<2048, 256, 0, stream>>>((const float4*)hs, (float4*)out, NTOK*D_/4);

  // 3. gather + rmsnorm1
  k_gather_rms<<<MSEL, 256, 0, stream>>>(hs, idxb, ln1_w, bufA, bufB);

  // 4. qkv projections
  dim3 gqkv(D_/64, MSEL/64);
  k_gemm<0><<<gqkv, 256, 0, stream>>>(bufB, wq, bq, nullptr, bufC, MSEL, D_, D_);
  k_gemm<0><<<gqkv, 256, 0, stream>>>(bufB, wk, bk, nullptr, bufD, MSEL, D_, D_);
  k_gemm<0><<<gqkv, 256, 0, stream>>>(bufB, wv, bv, nullptr, bufE, MSEL, D_, D_);

  // 5. attention
  dim3 gattn(KSEL/64, H_, B_);
  k_attn<<<gattn, 256, 0, stream>>>(bufC, bufD, bufE, bufF);

  // 6. o-proj + residual -> x2
  k_gemm<1><<<gqkv, 256, 0, stream>>>(bufF, wo, nullptr, bufA, bufG, MSEL, D_, D_);

  // 7. rmsnorm2
  k_rms<<<MSEL, 256, 0, stream>>>(bufG, ln2_w, bufB);

  // 8. gate/up fused -> inter
  dim3 gmlp(FF_/64, MSEL/64);
  k_dualgemm<<<gmlp, 256, 0, stream>>>(bufB, w_gate, w_up, inter, MSEL, FF_, D_);

  // 9. down proj + residual + gated scatter
  dim3 gdown(D_/64, MSEL/64);
  k_down_scatter<<<gdown, 256, 0, stream>>>(inter, w_down, bufG, bufA, gbuf, idxb,
                                            out, MSEL, D_, FF_);

  // 10. predictor (detached): h = gelu(hs@fc1+b) ; plog = h.fc2+b ; bce
  dim3 gpred(512/64, NTOK/64);
  k_gemm<2><<<gpred, 256, 0, stream>>>(hs, fc1_w, fc1_b, nullptr, hbuf, NTOK, 512, D_);
  k_pred_logits<<<NTOK/4, 256, 0, stream>>>(hbuf, fc2_w, fc2_b, plog);
  k_bce<<<1, 256, 0, stream>>>(plog, flags, out + (size_t)NTOK*D_ + 2);
}

// Round 6
// 1585.470 us; speedup vs baseline: 10.7884x; 2.9416x over previous
//
#include <hip/hip_runtime.h>
#include <cstdint>
#include <cstddef>

#define D_    2048
#define T_    4096
#define B_    2
#define KSEL  1024
#define FF_   8192
#define NTOK  (B_*T_)      // 8192
#define MSEL  (B_*KSEL)    // 2048
#define HD_   128
#define H_    16

typedef __attribute__((ext_vector_type(8))) short bf16x8;
typedef __attribute__((ext_vector_type(4))) float f32x4;
typedef __attribute__((ext_vector_type(4))) unsigned short us4;

__device__ __forceinline__ float sigmoidf_(float x){ return 1.0f/(1.0f+expf(-x)); }
__device__ __forceinline__ float geluf_(float x){ return 0.5f*x*(1.0f+erff(x*0.70710678118654752440f)); }

__device__ __forceinline__ unsigned short f2bf(float x){
  union { float f; unsigned u; } v; v.f = x;
  unsigned r = (v.u + 0x7FFFu + ((v.u >> 16) & 1u)) >> 16;   // RNE
  return (unsigned short)r;
}
__device__ __forceinline__ float bf2f(unsigned short s){
  union { unsigned u; float f; } v; v.u = ((unsigned)s) << 16; return v.f;
}

// async global->LDS, 16B per lane; lds dest is wave-uniform base + lane*16
__device__ __forceinline__ void gll16(const void* g, void* l) {
  __builtin_amdgcn_global_load_lds(
      (const __attribute__((address_space(1))) void*)g,
      (__attribute__((address_space(3))) void*)l, 16, 0, 0);
}

// ---------------- router logits (fp64 accum, exact ranking) ----------------
__global__ __launch_bounds__(256) void k_router_logits(const float* __restrict__ hs,
        const float* __restrict__ rw, float* __restrict__ logits) {
  int row = blockIdx.x;
  const float4* x = (const float4*)(hs + (size_t)row * D_);
  const float4* w = (const float4*)rw;
  int tid = threadIdx.x;
  double acc = 0.0;
  for (int i = tid; i < D_/4; i += 256) {
    float4 a = x[i]; float4 b = w[i];
    acc += (double)a.x*b.x + (double)a.y*b.y + (double)a.z*b.z + (double)a.w*b.w;
  }
  __shared__ double red[256];
  red[tid] = acc; __syncthreads();
  for (int s = 128; s > 0; s >>= 1) { if (tid < s) red[tid] += red[tid+s]; __syncthreads(); }
  if (tid == 0) logits[row] = (float)red[0];
}

// ---------------- top-k bitonic (desc value, tie -> lower idx) ----------------
__global__ __launch_bounds__(1024) void k_topk(const float* __restrict__ logits,
      int* __restrict__ idx_out, float* __restrict__ g_out, float* __restrict__ flags) {
  int b = blockIdx.x;
  int tid = threadIdx.x;
  __shared__ unsigned long long keys[T_];
  for (int i = tid; i < T_; i += 1024) {
    float v = logits[b*T_ + i];
    unsigned u = __float_as_uint(v);
    unsigned s = (u & 0x80000000u) ? ~u : (u | 0x80000000u);
    keys[i] = ((unsigned long long)s << 32) | (unsigned long long)(0xFFFFFFFFu - (unsigned)i);
    flags[b*T_ + i] = 0.0f;
  }
  __syncthreads();
  for (int size = 2; size <= T_; size <<= 1) {
    for (int stride = size >> 1; stride > 0; stride >>= 1) {
      for (int i = tid; i < T_; i += 1024) {
        int l = i ^ stride;
        if (l > i) {
          unsigned long long a = keys[i], c = keys[l];
          bool up = ((i & size) == 0);
          bool sw = up ? (a < c) : (a > c);
          if (sw) { keys[i] = c; keys[l] = a; }
        }
      }
      __syncthreads();
    }
  }
  if (tid < KSEL) {
    unsigned long long kk = keys[tid];
    unsigned s = (unsigned)(kk >> 32);
    unsigned u = (s & 0x80000000u) ? (s & 0x7FFFFFFFu) : ~s;
    float v = __uint_as_float(u);
    int t = (int)(0xFFFFFFFFu - (unsigned)(kk & 0xFFFFFFFFull));
    idx_out[b*KSEL + tid] = t;
    g_out[b*KSEL + tid] = sigmoidf_(v);
    flags[b*T_ + t] = 1.0f;
  }
}

// ---------------- router losses ----------------
__global__ __launch_bounds__(256) void k_router_loss(const float* __restrict__ logits,
      const float* __restrict__ flags, float* __restrict__ outp) {
  int tid = threadIdx.x;
  double bce = 0.0, z = 0.0;
  for (int i = tid; i < NTOK; i += 256) {
    float x = logits[i], y = flags[i];
    bce += (double)(fmaxf(x, 0.0f) - x*y + log1pf(expf(-fabsf(x))));
    z   += (double)x * (double)x;
  }
  __shared__ double r1[256], r2[256];
  r1[tid] = bce; r2[tid] = z; __syncthreads();
  for (int s = 128; s > 0; s >>= 1) {
    if (tid < s) { r1[tid] += r1[tid+s]; r2[tid] += r2[tid+s]; }
    __syncthreads();
  }
  if (tid == 0) {
    outp[0] = (float)(r1[0] / (double)NTOK);
    outp[1] = (float)(r2[0] / (double)NTOK * 1e-4);
  }
}

__global__ __launch_bounds__(256) void k_bce(const float* __restrict__ x,
      const float* __restrict__ y, float* __restrict__ outp) {
  int tid = threadIdx.x;
  double bce = 0.0;
  for (int i = tid; i < NTOK; i += 256) {
    float xv = x[i], yv = y[i];
    bce += (double)(fmaxf(xv, 0.0f) - xv*yv + log1pf(expf(-fabsf(xv))));
  }
  __shared__ double r1[256];
  r1[tid] = bce; __syncthreads();
  for (int s = 128; s > 0; s >>= 1) { if (tid < s) r1[tid] += r1[tid+s]; __syncthreads(); }
  if (tid == 0) outp[0] = (float)(r1[0] / (double)NTOK);
}

// ---------------- copy hs -> out (fp32) and hs -> bf16 ----------------
__global__ __launch_bounds__(256) void k_copy2(const float4* __restrict__ src,
      float4* __restrict__ dst, unsigned short* __restrict__ hsb, int n4) {
  int i = blockIdx.x*256 + threadIdx.x;
  int stride = gridDim.x*256;
  for (; i < n4; i += stride) {
    float4 v = src[i];
    dst[i] = v;
    us4 o; o.x = f2bf(v.x); o.y = f2bf(v.y); o.z = f2bf(v.z); o.w = f2bf(v.w);
    *(us4*)(hsb + (size_t)i*4) = o;
  }
}

// ---------------- weight fp32 [K,N] -> bf16 [N,K] (transpose) ----------------
__global__ __launch_bounds__(256) void k_w2bt(const float* __restrict__ W,
      unsigned short* __restrict__ Wt, int K, int N) {
  __shared__ float t[64][65];
  int k0 = blockIdx.y*64, n0 = blockIdx.x*64;
  int tid = threadIdx.x;
  int lr = tid >> 4, lc = (tid & 15) * 4;
  #pragma unroll
  for (int j = 0; j < 4; ++j) {
    float4 v = *(const float4*)(W + (size_t)(k0 + lr + j*16)*N + n0 + lc);
    t[lr + j*16][lc+0] = v.x; t[lr + j*16][lc+1] = v.y;
    t[lr + j*16][lc+2] = v.z; t[lr + j*16][lc+3] = v.w;
  }
  __syncthreads();
  #pragma unroll
  for (int j = 0; j < 4; ++j) {
    int n = lr + j*16;
    us4 o;
    o.x = f2bf(t[lc+0][n]); o.y = f2bf(t[lc+1][n]);
    o.z = f2bf(t[lc+2][n]); o.w = f2bf(t[lc+3][n]);
    *(us4*)(Wt + (size_t)(n0 + n)*K + k0 + lc) = o;
  }
}

// ---------------- gather + RMSNorm(ln1): x_sel fp32 + xa bf16 ----------------
__global__ __launch_bounds__(256) void k_gather_rms(const float* __restrict__ hs,
      const int* __restrict__ idx, const float* __restrict__ w,
      float* __restrict__ xsel, unsigned short* __restrict__ xab) {
  int row = blockIdx.x;
  int b = row >> 10;
  int t = idx[row];
  const float4* src = (const float4*)(hs + ((size_t)(b*T_ + t)) * D_);
  float4* xs4 = (float4*)(xsel + (size_t)row*D_);
  const float4* w4 = (const float4*)w;
  int tid = threadIdx.x;
  float4 loc[2];
  double ss = 0.0;
  #pragma unroll
  for (int j = 0; j < 2; ++j) {
    float4 v = src[tid + j*256];
    loc[j] = v;
    ss += (double)v.x*v.x + (double)v.y*v.y + (double)v.z*v.z + (double)v.w*v.w;
  }
  __shared__ double red[256];
  red[tid] = ss; __syncthreads();
  for (int s = 128; s > 0; s >>= 1) { if (tid < s) red[tid] += red[tid+s]; __syncthreads(); }
  float rms = (float)(1.0 / sqrt(red[0] / (double)D_ + 1e-6));
  #pragma unroll
  for (int j = 0; j < 2; ++j) {
    float4 v = loc[j];
    float4 ww = w4[tid + j*256];
    xs4[tid + j*256] = v;
    us4 o;
    o.x = f2bf(v.x*rms*ww.x); o.y = f2bf(v.y*rms*ww.y);
    o.z = f2bf(v.z*rms*ww.z); o.w = f2bf(v.w*rms*ww.w);
    *(us4*)(xab + (size_t)row*D_ + (size_t)(tid + j*256)*4) = o;
  }
}

// ---------------- RMSNorm fp32 in -> bf16 out ----------------
__global__ __launch_bounds__(256) void k_rms(const float* __restrict__ x,
      const float* __restrict__ w, unsigned short* __restrict__ yb) {
  int row = blockIdx.x;
  const float4* xr = (const float4*)(x + (size_t)row*D_);
  const float4* w4 = (const float4*)w;
  int tid = threadIdx.x;
  float4 loc[2];
  double ss = 0.0;
  #pragma unroll
  for (int j = 0; j < 2; ++j) {
    float4 v = xr[tid + j*256];
    loc[j] = v;
    ss += (double)v.x*v.x + (double)v.y*v.y + (double)v.z*v.z + (double)v.w*v.w;
  }
  __shared__ double red[256];
  red[tid] = ss; __syncthreads();
  for (int s = 128; s > 0; s >>= 1) { if (tid < s) red[tid] += red[tid+s]; __syncthreads(); }
  float rms = (float)(1.0 / sqrt(red[0] / (double)D_ + 1e-6));
  #pragma unroll
  for (int j = 0; j < 2; ++j) {
    float4 v = loc[j];
    float4 ww = w4[tid + j*256];
    us4 o;
    o.x = f2bf(v.x*rms*ww.x); o.y = f2bf(v.y*rms*ww.y);
    o.z = f2bf(v.z*rms*ww.z); o.w = f2bf(v.w*rms*ww.w);
    *(us4*)(yb + (size_t)row*D_ + (size_t)(tid + j*256)*4) = o;
  }
}

// ---------------- bf16 MFMA GEMM, m97 structure: 128x128 tile, BK=32 ----------------
// A bf16 [M,K] row-major; Bt bf16 [N,K] row-major (pre-transposed weights).
// EPI: 0=QKV(bias->bf16) 1=OPROJ(+res->fp32) 2=GATE(->bf16) 3=UP(silu(gate)*acc->bf16, in-place ok)
//      4=DOWN(+x2, gated scatter->out fp32) 5=PRED(gelu(+bias)->bf16)
template<int EPI>
__global__ __launch_bounds__(256) void k_gemm_bf(
    const unsigned short* __restrict__ A, const unsigned short* __restrict__ Bt,
    const float* __restrict__ bias, const float* __restrict__ res,
    const unsigned short* __restrict__ gatep, const float* __restrict__ xsel,
    const float* __restrict__ gbuf, const int* __restrict__ idxb,
    void* __restrict__ Cout, int M, int N, int K) {
  __shared__ __align__(16) unsigned short As[128*32];
  __shared__ __align__(16) unsigned short Bs[128*32];
  int tid = threadIdx.x;
  int lane = tid & 63, wid = tid >> 6;
  int brow = blockIdx.y * 128, bcol = blockIdx.x * 128;
  int wr = (wid >> 1) * 64, wc = (wid & 1) * 64;

  // staging: thread t -> row (t>>2) of 64-row half, kchunk (t&3)*8; LDS addr wid*512+l*8 == row*32+k (ushort)
  const unsigned short* Ap = A + (size_t)(brow + (tid >> 2)) * K + (tid & 3) * 8;
  const unsigned short* Bp = Bt + (size_t)(bcol + (tid >> 2)) * K + (tid & 3) * 8;
  unsigned short* lA0 = As + wid * 512;
  unsigned short* lA1 = As + 2048 + wid * 512;
  unsigned short* lB0 = Bs + wid * 512;
  unsigned short* lB1 = Bs + 2048 + wid * 512;
  size_t rowskip = (size_t)64 * K;

  f32x4 acc[4][4];
  #pragma unroll
  for (int m = 0; m < 4; ++m)
    #pragma unroll
    for (int n = 0; n < 4; ++n) acc[m][n] = (f32x4){0.f,0.f,0.f,0.f};

  int ar = wr + (lane & 15);
  int br = wc + (lane & 15);
  int ko = (lane >> 4) * 8;
  int nk = K >> 5;
  for (int kt = 0; kt < nk; ++kt) {
    const unsigned short* a0 = Ap + kt*32;
    const unsigned short* b0 = Bp + kt*32;
    gll16(a0, lA0);
    gll16(a0 + rowskip, lA1);
    gll16(b0, lB0);
    gll16(b0 + rowskip, lB1);
    __syncthreads();
    bf16x8 af[4], bfr[4];
    #pragma unroll
    for (int m = 0; m < 4; ++m) af[m] = *(const bf16x8*)&As[(ar + m*16)*32 + ko];
    #pragma unroll
    for (int n = 0; n < 4; ++n) bfr[n] = *(const bf16x8*)&Bs[(br + n*16)*32 + ko];
    #pragma unroll
    for (int m = 0; m < 4; ++m)
      #pragma unroll
      for (int n = 0; n < 4; ++n)
        acc[m][n] = __builtin_amdgcn_mfma_f32_16x16x32_bf16(af[m], bfr[n], acc[m][n], 0, 0, 0);
    __syncthreads();
  }

  // epilogue: C/D layout col=lane&15, row=(lane>>4)*4+reg
  int r0 = brow + wr + (lane >> 4) * 4;
  int c0 = bcol + wc + (lane & 15);
  #pragma unroll
  for (int m = 0; m < 4; ++m) {
    #pragma unroll
    for (int reg = 0; reg < 4; ++reg) {
      int r = r0 + m*16 + reg;
      #pragma unroll
      for (int n = 0; n < 4; ++n) {
        int c = c0 + n*16;
        float val = acc[m][n][reg];
        if (EPI == 0) {
          ((unsigned short*)Cout)[(size_t)r*N + c] = f2bf(val + bias[c]);
        } else if (EPI == 1) {
          ((float*)Cout)[(size_t)r*N + c] = val + res[(size_t)r*N + c];
        } else if (EPI == 2) {
          ((unsigned short*)Cout)[(size_t)r*N + c] = f2bf(val);
        } else if (EPI == 3) {
          float g = bf2f(gatep[(size_t)r*N + c]);
          ((unsigned short*)Cout)[(size_t)r*N + c] = f2bf(g * sigmoidf_(g) * val);
        } else if (EPI == 4) {
          int bb = r >> 10;
          int t = idxb[r];
          float gv = gbuf[r];
          float xs = xsel[(size_t)r*N + c];
          float x2v = res[(size_t)r*N + c];
          float nv = xs + gv * (x2v + val - xs);
          ((float*)Cout)[((size_t)(bb*T_ + t))*D_ + c] = nv;
        } else {
          ((unsigned short*)Cout)[(size_t)r*N + c] = f2bf(geluf_(val + bias[c]));
        }
      }
    }
  }
}

// ---------------- flash attention, bf16 in (q,k,v) / bf16 out ----------------
__global__ __launch_bounds__(256) void k_attn(const unsigned short* __restrict__ Q,
    const unsigned short* __restrict__ Km, const unsigned short* __restrict__ V,
    unsigned short* __restrict__ O) {
  int qt = gridDim.x - 1 - blockIdx.x;   // heavy tiles first
  int h  = blockIdx.y;
  int b  = blockIdx.z;
  __shared__ float Qs[64][132];
  __shared__ float KVs[64][140];
  __shared__ float Ss[64][68];
  __shared__ float mrow[64], lrow[64];
  int tid = threadIdx.x;
  size_t base = ((size_t)b*KSEL)*D_ + (size_t)h*HD_;
  #pragma unroll
  for (int i = 0; i < 8; ++i) {
    int f = tid + i*256; int r = f >> 5; int c = (f & 31) << 2;
    us4 hv = *(const us4*)(Q + base + (size_t)(qt*64 + r)*D_ + c);
    float4 w; w.x = bf2f(hv.x); w.y = bf2f(hv.y); w.z = bf2f(hv.z); w.w = bf2f(hv.w);
    *(float4*)&Qs[r][c] = w;
  }
  if (tid < 64) { mrow[tid] = -1e30f; lrow[tid] = 0.0f; }
  float acc[32];
  #pragma unroll
  for (int i = 0; i < 32; ++i) acc[i] = 0.0f;
  int tx = tid & 15, ty = tid >> 4;
  int rr = tid >> 2, seg = (tid & 3) * 16;
  int g4 = tid & 3;
  int colA = g4 * 32;
  int vbase = g4 * 36;                   // swizzled V base
  __syncthreads();
  const float sc = 0.08838834764831845f;
  for (int kt = 0; kt <= qt; ++kt) {
    #pragma unroll
    for (int i = 0; i < 8; ++i) {
      int f = tid + i*256; int r = f >> 5; int c = (f & 31) << 2;
      us4 hv = *(const us4*)(Km + base + (size_t)(kt*64 + r)*D_ + c);
      float4 w; w.x = bf2f(hv.x); w.y = bf2f(hv.y); w.z = bf2f(hv.z); w.w = bf2f(hv.w);
      *(float4*)&KVs[r][c] = w;
    }
    __syncthreads();
    float s[4][4];
    #pragma unroll
    for (int i = 0; i < 4; ++i)
      #pragma unroll
      for (int j = 0; j < 4; ++j) s[i][j] = 0.0f;
    #pragma unroll 4
    for (int d = 0; d < HD_; d += 4) {
      float4 qv[4], kv[4];
      #pragma unroll
      for (int i = 0; i < 4; ++i) qv[i] = *(const float4*)&Qs[ty + 16*i][d];
      #pragma unroll
      for (int j = 0; j < 4; ++j) kv[j] = *(const float4*)&KVs[tx + 16*j][d];
      #pragma unroll
      for (int i = 0; i < 4; ++i)
        #pragma unroll
        for (int j = 0; j < 4; ++j) {
          s[i][j] = fmaf(qv[i].x, kv[j].x, s[i][j]);
          s[i][j] = fmaf(qv[i].y, kv[j].y, s[i][j]);
          s[i][j] = fmaf(qv[i].z, kv[j].z, s[i][j]);
          s[i][j] = fmaf(qv[i].w, kv[j].w, s[i][j]);
        }
    }
    #pragma unroll
    for (int i = 0; i < 4; ++i)
      #pragma unroll
      for (int j = 0; j < 4; ++j) {
        int qpos = qt*64 + ty + 16*i, kpos = kt*64 + tx + 16*j;
        float v = s[i][j] * sc;
        if (kpos > qpos) v = -1e9f;
        Ss[ty + 16*i][tx + 16*j] = v;
      }
    __syncthreads();
    float mold = mrow[rr];
    float tmax = -1e30f;
    for (int c2 = 0; c2 < 16; ++c2) tmax = fmaxf(tmax, Ss[rr][seg + c2]);
    tmax = fmaxf(tmax, __shfl_xor(tmax, 1));
    tmax = fmaxf(tmax, __shfl_xor(tmax, 2));
    float mnew = fmaxf(mold, tmax);
    float psum = 0.0f;
    for (int c2 = 0; c2 < 16; ++c2) {
      float p = expf(Ss[rr][seg + c2] - mnew);
      Ss[rr][seg + c2] = p;
      psum += p;
    }
    psum += __shfl_xor(psum, 1);
    psum += __shfl_xor(psum, 2);
    float scale = expf(mold - mnew);
    if (g4 == 0) { mrow[rr] = mnew; lrow[rr] = lrow[rr]*scale + psum; }
    __syncthreads();
    #pragma unroll
    for (int i = 0; i < 8; ++i) {
      int f = tid + i*256; int r = f >> 5; int c = (f & 31) << 2;
      int pc = c + ((c >> 5) << 2);
      us4 hv = *(const us4*)(V + base + (size_t)(kt*64 + r)*D_ + c);
      float4 w; w.x = bf2f(hv.x); w.y = bf2f(hv.y); w.z = bf2f(hv.z); w.w = bf2f(hv.w);
      *(float4*)&KVs[r][pc] = w;
    }
    #pragma unroll
    for (int i = 0; i < 32; ++i) acc[i] *= scale;
    __syncthreads();
    for (int j = 0; j < 64; ++j) {
      float p = Ss[rr][j];
      #pragma unroll
      for (int c4 = 0; c4 < 8; ++c4) {
        float4 vv = *(const float4*)&KVs[j][vbase + c4*4];
        acc[c4*4+0] = fmaf(p, vv.x, acc[c4*4+0]);
        acc[c4*4+1] = fmaf(p, vv.y, acc[c4*4+1]);
        acc[c4*4+2] = fmaf(p, vv.z, acc[c4*4+2]);
        acc[c4*4+3] = fmaf(p, vv.w, acc[c4*4+3]);
      }
    }
    __syncthreads();
  }
  float invl = 1.0f / lrow[rr];
  unsigned short* orow = O + base + (size_t)(qt*64 + rr)*D_ + colA;
  #pragma unroll
  for (int c4 = 0; c4 < 8; ++c4) {
    us4 ov;
    ov.x = f2bf(acc[c4*4+0]*invl); ov.y = f2bf(acc[c4*4+1]*invl);
    ov.z = f2bf(acc[c4*4+2]*invl); ov.w = f2bf(acc[c4*4+3]*invl);
    *(us4*)(orow + c4*4) = ov;
  }
}

// ---------------- predictor logits: h bf16 [8192,512] . fc2_w ----------------
__global__ __launch_bounds__(256) void k_pred_logits(const unsigned short* __restrict__ h,
      const float* __restrict__ fc2w, const float* __restrict__ fc2b, float* __restrict__ plog) {
  int wid = threadIdx.x >> 6, lane = threadIdx.x & 63;
  int row = blockIdx.x*4 + wid;
  const unsigned short* hr = h + (size_t)row*512 + lane*8;
  bf16x8 hv = *(const bf16x8*)hr;
  float acc = 0.0f;
  #pragma unroll
  for (int j = 0; j < 8; ++j)
    acc += bf2f((unsigned short)hv[j]) * fc2w[lane*8 + j];
  for (int off = 32; off > 0; off >>= 1) acc += __shfl_down(acc, off);
  if (lane == 0) plog[row] = acc + fc2b[0];
}

extern "C" void kernel_launch(void* const* d_in, const int* in_sizes, int n_in,
                              void* d_out, int out_size, void* d_ws, size_t ws_size,
                              hipStream_t stream) {
  const float* hs      = (const float*)d_in[0];
  const float* router_w= (const float*)d_in[1];
  const float* fc1_w   = (const float*)d_in[2];
  const float* fc1_b   = (const float*)d_in[3];
  const float* fc2_w   = (const float*)d_in[4];
  const float* fc2_b   = (const float*)d_in[5];
  const float* ln1_w   = (const float*)d_in[6];
  const float* ln2_w   = (const float*)d_in[7];
  const float* wq      = (const float*)d_in[8];
  const float* bq      = (const float*)d_in[9];
  const float* wk      = (const float*)d_in[10];
  const float* bk      = (const float*)d_in[11];
  const float* wv      = (const float*)d_in[12];
  const float* bv      = (const float*)d_in[13];
  const float* wo      = (const float*)d_in[14];
  const float* w_gate  = (const float*)d_in[15];
  const float* w_up    = (const float*)d_in[16];
  const float* w_down  = (const float*)d_in[17];
  float* out = (float*)d_out;

  float* ws = (float*)d_ws;
  float* logits = ws;                       // 8192
  float* flags  = ws + 8192;                // 8192
  int*   idxb   = (int*)(ws + 16384);       // 2048
  float* gbuf   = ws + 18432;               // 2048
  float* plog   = ws + 20480;               // 8192

  size_t off = 32768;
  float* x_sel = ws + off;                          off += 4194304;  // [2048,2048] fp32
  float* x2    = ws + off;                          off += 4194304;  // [2048,2048] fp32
  unsigned short* xab   = (unsigned short*)(ws + off); off += 2097152; // [2048,2048] bf16
  unsigned short* xmb   = (unsigned short*)(ws + off); off += 2097152;
  unsigned short* ob    = (unsigned short*)(ws + off); off += 2097152;
  unsigned short* qb    = (unsigned short*)(ws + off); off += 2097152;
  unsigned short* kb    = (unsigned short*)(ws + off); off += 2097152;
  unsigned short* vb    = (unsigned short*)(ws + off); off += 2097152;
  unsigned short* hsb   = (unsigned short*)(ws + off); off += 8388608; // [8192,2048] bf16; DEAD after predictor
  unsigned short* gateb = hsb;                                         // [2048,8192] bf16 (aliases hsb; also holds silu(g)*u in-place)
  unsigned short* hpred = (unsigned short*)(ws + off); off += 2097152; // [8192,512]  bf16
  unsigned short* wq_t  = (unsigned short*)(ws + off); off += 2097152; // [2048,2048]
  unsigned short* wk_t  = (unsigned short*)(ws + off); off += 2097152;
  unsigned short* wv_t  = (unsigned short*)(ws + off); off += 2097152;
  unsigned short* wo_t  = (unsigned short*)(ws + off); off += 2097152;
  unsigned short* wmlp  = (unsigned short*)(ws + off); off += 8388608; // shared wg_t/wu_t/wd_t (JIT convert)
  unsigned short* fc1_t = (unsigned short*)(ws + off); off += 524288;  // [512,2048]
  // peak ≈ 195 MB

  // 1. router
  k_router_logits<<<NTOK, 256, 0, stream>>>(hs, router_w, logits);
  k_topk<<<B_, 1024, 0, stream>>>(logits, idxb, gbuf, flags);
  k_router_loss<<<1, 256, 0, stream>>>(logits, flags, out + (size_t)NTOK*D_);

  // 2. base copy + bf16 hs
  k_copy2<<<2048, 256, 0, stream>>>((const float4*)hs, (float4*)out, hsb, NTOK*D_/4);

  // 3. predictor FIRST (frees hsb for gateb): h = gelu(hs@fc1+b); plog; bce
  k_w2bt<<<dim3(8,32), 256, 0, stream>>>(fc1_w, fc1_t, D_, 512);
  dim3 gpred(4, 64);
  k_gemm_bf<5><<<gpred, 256, 0, stream>>>(hsb, fc1_t, fc1_b, nullptr, nullptr, nullptr, nullptr, nullptr, hpred, NTOK, 512, D_);
  k_pred_logits<<<NTOK/4, 256, 0, stream>>>(hpred, fc2_w, fc2_b, plog);
  k_bce<<<1, 256, 0, stream>>>(plog, flags, out + (size_t)NTOK*D_ + 2);

  // 4. attention-path weight converts
  k_w2bt<<<dim3(32,32), 256, 0, stream>>>(wq, wq_t, D_, D_);
  k_w2bt<<<dim3(32,32), 256, 0, stream>>>(wk, wk_t, D_, D_);
  k_w2bt<<<dim3(32,32), 256, 0, stream>>>(wv, wv_t, D_, D_);
  k_w2bt<<<dim3(32,32), 256, 0, stream>>>(wo, wo_t, D_, D_);

  // 5. gather + rmsnorm1
  k_gather_rms<<<MSEL, 256, 0, stream>>>(hs, idxb, ln1_w, x_sel, xab);

  // 6. QKV projections (bf16 MFMA)
  dim3 g16(16, 16);
  k_gemm_bf<0><<<g16, 256, 0, stream>>>(xab, wq_t, bq, nullptr, nullptr, nullptr, nullptr, nullptr, qb, MSEL, D_, D_);
  k_gemm_bf<0><<<g16, 256, 0, stream>>>(xab, wk_t, bk, nullptr, nullptr, nullptr, nullptr, nullptr, kb, MSEL, D_, D_);
  k_gemm_bf<0><<<g16, 256, 0, stream>>>(xab, wv_t, bv, nullptr, nullptr, nullptr, nullptr, nullptr, vb, MSEL, D_, D_);

  // 7. attention
  dim3 gattn(KSEL/64, H_, B_);
  k_attn<<<gattn, 256, 0, stream>>>(qb, kb, vb, ob);

  // 8. o-proj + residual -> x2 (fp32)
  k_gemm_bf<1><<<g16, 256, 0, stream>>>(ob, wo_t, nullptr, x_sel, nullptr, nullptr, nullptr, nullptr, x2, MSEL, D_, D_);

  // 9. rmsnorm2 -> xm bf16
  k_rms<<<MSEL, 256, 0, stream>>>(x2, ln2_w, xmb);

  // 10. MLP with JIT weight conversion into shared wmlp buffer
  dim3 gmlp(64, 16);
  k_w2bt<<<dim3(128,32), 256, 0, stream>>>(w_gate, wmlp, D_, FF_);
  k_gemm_bf<2><<<gmlp, 256, 0, stream>>>(xmb, wmlp, nullptr, nullptr, nullptr, nullptr, nullptr, nullptr, gateb, MSEL, FF_, D_);
  k_w2bt<<<dim3(128,32), 256, 0, stream>>>(w_up, wmlp, D_, FF_);
  k_gemm_bf<3><<<gmlp, 256, 0, stream>>>(xmb, wmlp, nullptr, nullptr, gateb, nullptr, nullptr, nullptr, gateb, MSEL, FF_, D_);
  k_w2bt<<<dim3(32,128), 256, 0, stream>>>(w_down, wmlp, FF_, D_);
  k_gemm_bf<4><<<g16, 256, 0, stream>>>(gateb, wmlp, nullptr, x2, nullptr, x_sel, gbuf, idxb, out, MSEL, D_, FF_);
}